// Round 5
// baseline (500.012 us; speedup 1.0000x reference)
//
#include <hip/hip_runtime.h>
#include <hip/hip_bf16.h>
#include <cstdint>
#include <cstddef>

// TripletLoss: inputs (8192,128) fp32, targets (8192,) int32, 64 classes.
// out[0] = loss, out[1..] = dist (8192x8192) row-major fp32.
// v6: row-panel ownership. v5's counters (WRITE 470MB = 1.75x amp, FETCH
// 110MB) proved the limiter is partial-line RMW at tile boundaries: the
// out+1 phase makes every 512B column-segment edge a partial cache line,
// and concurrent blocks on different XCDs thrash those lines.
// Fix: one block owns 128 FULL rows x 1024 cols (grid 64 bm x 8 chunks,
// bm-fast) -> all interior segment boundaries written by the same block,
// same XCD, temporally adjacent -> full-line merge in L2. Remaining shared
// lines: chunk seams only (~3.7MB). To store row-contiguously with NO LDS:
// MFMA operand order swapped (mfma(bfr, af)) so each lane's f32x4 is 4
// consecutive COLUMNS of one row -> direct dword-aligned dwordx4 stores
// (1-in-4 crosses a line; same-block coverage makes it free in DRAM terms).
// Row hard-pos/neg reduce is now lane-local: register accumulate across the
// whole chunk, 2 shfl_xor, 8 atomics/wave. Zero LDS, zero barriers.

#define NROWS 8192
#define DIMK  128
#define MARGIN 0.3f
#define NCH   8     // column chunks (blocks per row panel)
#define TPC   8     // 128-col sub-tiles per chunk

typedef __bf16 bf16x8 __attribute__((ext_vector_type(8)));
typedef float  f32x4  __attribute__((ext_vector_type(4)));
typedef float  f32x2  __attribute__((ext_vector_type(2)));
typedef int    i32x4  __attribute__((ext_vector_type(4)));

// 16B store with only 4B alignment guarantee (dist = out+1). Backend emits
// global_store_dwordx4; dword-aligned multi-dword is legal on CDNA.
struct __attribute__((packed, aligned(4))) f32x4_u {
    f32x4 v;
};

__device__ __forceinline__ unsigned short f2bf(float f) {
    // round-to-nearest-even fp32 -> bf16
    unsigned u = __float_as_uint(f);
    u += 0x7fffu + ((u >> 16) & 1u);
    return (unsigned short)(u >> 16);
}

// prep: bf16-convert X into LINEAR Xb, row sq-norms from the ROUNDED
// values, init ap/an. grid 2048 x 256 (one wave per row).
__global__ __launch_bounds__(256) void prep_kernel(
    const float* __restrict__ X, unsigned short* __restrict__ Xb,
    float* __restrict__ sq, int* __restrict__ ap, int* __restrict__ an)
{
    const int t = blockIdx.x * 256 + threadIdx.x;
    if (t < NROWS) { ap[t] = 0; an[t] = 0x7f800000; }  // 0.0f / +inf
    const int row  = t >> 6;
    const int lane = t & 63;
    const f32x2 v = *(const f32x2*)(X + (size_t)row * DIMK + lane * 2);
    const unsigned short b0 = f2bf(v[0]);
    const unsigned short b1 = f2bf(v[1]);
    *(unsigned*)(Xb + (size_t)row * DIMK + lane * 2) =
        (unsigned)b0 | ((unsigned)b1 << 16);
    const float f0 = __uint_as_float((unsigned)b0 << 16);
    const float f1 = __uint_as_float((unsigned)b1 << 16);
    float s = f0 * f0 + f1 * f1;
    #pragma unroll
    for (int off = 32; off; off >>= 1) s += __shfl_xor(s, off);
    if (lane == 0) sq[row] = s;
}

__global__ __launch_bounds__(256, 3) void dist_kernel(
    const unsigned short* __restrict__ Xb, const float* __restrict__ sq,
    const int* __restrict__ tgt, float* __restrict__ dist,
    int* __restrict__ ap, int* __restrict__ an)
{
    const int t    = threadIdx.x;
    const int bm   = blockIdx.x;               // row panel (fast grid dim)
    const int ch   = blockIdx.y;               // column chunk
    const int lane = t & 63, wave = t >> 6;
    const int wm   = (wave >> 1) << 6;         // wave's 64-row half
    const int wn   = (wave & 1) << 6;          // wave's 64-col half
    const int l15  = lane & 15, quad = lane >> 4;
    const int rbase = (bm << 7) + wm;
    const float INF = __int_as_float(0x7f800000);

    // ---- per-row state, loaded once, reused across the whole chunk ----
    // lane's rows: rg[mi] = rbase + mi*16 + l15 (transposed C layout).
    bf16x8 af[4][4];                           // [ks][mi] A fragments
    const unsigned short* Arow = Xb + (size_t)(rbase + l15) * DIMK;
    #pragma unroll
    for (int ks = 0; ks < 4; ks++)
        #pragma unroll
        for (int mi = 0; mi < 4; mi++)
            af[ks][mi] = *(const bf16x8*)(Arow + mi * 16 * DIMK + ks * 32 + quad * 8);

    int rg[4]; float sqr[4]; int trg[4];
    #pragma unroll
    for (int mi = 0; mi < 4; mi++) {
        rg[mi]  = rbase + mi * 16 + l15;
        sqr[mi] = sq[rg[mi]];
        trg[mi] = tgt[rg[mi]];
    }
    float apv[4] = {-1.f, -1.f, -1.f, -1.f};
    float anv[4] = {INF, INF, INF, INF};

    // ---- loop over the chunk's 8 sub-tiles: MFMA -> convert -> store ----
    for (int it = 0; it < TPC; ++it) {
        const int cw = ((ch * TPC + it) << 7) + wn;   // wave's 64-col strip
        const unsigned short* Brow = Xb + (size_t)(cw + l15) * DIMK;

        f32x4 acc[4][4];
        #pragma unroll
        for (int mi = 0; mi < 4; mi++)
            #pragma unroll
            for (int ni = 0; ni < 4; ni++)
                acc[mi][ni] = (f32x4){0.f, 0.f, 0.f, 0.f};

        #pragma unroll
        for (int ks = 0; ks < 4; ks++) {
            bf16x8 bfr[4];
            #pragma unroll
            for (int ni = 0; ni < 4; ni++)
                bfr[ni] = *(const bf16x8*)(Brow + ni * 16 * DIMK + ks * 32 + quad * 8);
            // operand order swapped vs v1-v5: lane's C regs = 4 consecutive
            // COLUMNS (quad*4+reg) of one row (l15).
            #pragma unroll
            for (int mi = 0; mi < 4; mi++)
                #pragma unroll
                for (int ni = 0; ni < 4; ni++)
                    acc[mi][ni] = __builtin_amdgcn_mfma_f32_16x16x32_bf16(
                        bfr[ni], af[ks][mi], acc[mi][ni], 0, 0, 0);
        }

        #pragma unroll
        for (int ni = 0; ni < 4; ni++) {
            const int c0 = cw + ni * 16 + quad * 4;
            const f32x4 sqc = *(const f32x4*)(sq + c0);
            const i32x4 tc  = *(const i32x4*)(tgt + c0);
            #pragma unroll
            for (int mi = 0; mi < 4; mi++) {
                f32x4 d4;
                #pragma unroll
                for (int j = 0; j < 4; j++) {
                    const float sqd = sqr[mi] + sqc[j] - 2.0f * acc[mi][ni][j];
                    float d = sqd > 0.0f ? sqrtf(sqd) : 0.0f;
                    if (rg[mi] == c0 + j) d = 0.0f;    // exact diagonal
                    d4[j] = d;
                    const bool same = (trg[mi] == tc[j]);
                    apv[mi] = fmaxf(apv[mi], same ? d : -1.f);
                    anv[mi] = fminf(anv[mi], same ? INF : d);
                }
                ((f32x4_u*)(dist + (size_t)rg[mi] * NROWS + c0))->v = d4;
            }
        }
    }

    // ---- finalize: combine the 4 quads holding the same row, commit ----
    #pragma unroll
    for (int mi = 0; mi < 4; mi++) {
        apv[mi] = fmaxf(apv[mi], __shfl_xor(apv[mi], 16));
        apv[mi] = fmaxf(apv[mi], __shfl_xor(apv[mi], 32));
        anv[mi] = fminf(anv[mi], __shfl_xor(anv[mi], 16));
        anv[mi] = fminf(anv[mi], __shfl_xor(anv[mi], 32));
    }
    if (quad == 0) {
        #pragma unroll
        for (int mi = 0; mi < 4; mi++) {
            atomicMax(ap + rg[mi], __float_as_int(apv[mi]));
            atomicMin(an + rg[mi], __float_as_int(anv[mi]));
        }
    }
}

__global__ __launch_bounds__(256) void loss_kernel(
    const int* __restrict__ ap, const int* __restrict__ an,
    float* __restrict__ out)
{
    __shared__ float red[4];
    float s = 0.0f;
    for (int i = threadIdx.x; i < NROWS; i += 256) {
        const float v = __int_as_float(ap[i]) - __int_as_float(an[i]) + MARGIN;
        s += v > 0.0f ? v : 0.0f;
    }
    #pragma unroll
    for (int off = 32; off; off >>= 1) s += __shfl_xor(s, off);
    if ((threadIdx.x & 63) == 0) red[threadIdx.x >> 6] = s;
    __syncthreads();
    if (threadIdx.x == 0)
        out[0] = (red[0] + red[1] + red[2] + red[3]) * (1.0f / NROWS);
}

extern "C" void kernel_launch(void* const* d_in, const int* in_sizes, int n_in,
                              void* d_out, int out_size, void* d_ws, size_t ws_size,
                              hipStream_t stream)
{
    const float* X   = (const float*)d_in[0];
    const int*   tgt = (const int*)d_in[1];
    float*       out = (float*)d_out;

    // ws layout: Xb bf16 8192x128 linear (2 MB) | sq (32 KB) | ap | an
    unsigned short* Xb = (unsigned short*)d_ws;
    float* sq = (float*)((char*)d_ws + (size_t)NROWS * DIMK * 2);
    int*   ap = (int*)(sq + NROWS);
    int*   an = ap + NROWS;

    prep_kernel<<<(NROWS * 64) / 256, 256, 0, stream>>>(X, Xb, sq, ap, an);

    dim3 grid(64, NCH);   // x = bm (fast: no shared lines between neighbors)
    dist_kernel<<<grid, 256, 0, stream>>>(Xb, sq, tgt, out + 1, ap, an);

    loss_kernel<<<1, 256, 0, stream>>>(ap, an, out);
}

// Round 6
// 339.597 us; speedup vs baseline: 1.4724x; 1.4724x over previous
//
#include <hip/hip_runtime.h>
#include <hip/hip_bf16.h>
#include <cstdint>
#include <cstddef>

// TripletLoss: inputs (8192,128) fp32, targets (8192,) int32, 64 classes.
// out[0] = loss, out[1..] = dist (8192x8192) row-major fp32.
// v7 = v4's store pattern (the only one with ~1.05x write amp: 16B-aligned
// shifted stores, full 64B sectors per instruction, 512B contiguous per
// half-wave) + v6's register layout + 4 blocks/CU:
//  - operand-swapped MFMA (lane = 4 consecutive cols of one row, verified in
//    v6) -> C-staging is 16 ds_write_b128/thread (swizzled) instead of 64
//    scalar ds_write_b32.
//  - row hard-pos/neg reduce done lane-local in the convert phase (register
//    accumulate, 2 shfl_xor, atomics) -> readback is a pure LDS->global copy.
//  - no A/B LDS staging (direct global frag loads; Xb 2MB is L2/L3-resident,
//    v5-verified) -> C tile through 32KB LDS in two 64-row halves ->
//    4 blocks/CU (launch_bounds(256,4)), 2 barriers per half.
//  - bm-fast grid kept from v4: bn-seam neighbors (which share the out+1
//    misaligned edge lines) land on the SAME XCD (64%8==0) -> L2 merge works.

#define NROWS 8192
#define DIMK  128
#define MARGIN 0.3f

typedef __bf16 bf16x8 __attribute__((ext_vector_type(8)));
typedef float  f32x4  __attribute__((ext_vector_type(4)));
typedef float  f32x2  __attribute__((ext_vector_type(2)));
typedef int    i32x4  __attribute__((ext_vector_type(4)));

__device__ __forceinline__ unsigned short f2bf(float f) {
    // round-to-nearest-even fp32 -> bf16
    unsigned u = __float_as_uint(f);
    u += 0x7fffu + ((u >> 16) & 1u);
    return (unsigned short)(u >> 16);
}

// prep: bf16-convert X into LINEAR Xb, row sq-norms from the ROUNDED values,
// init ap/an. grid 2048 x 256 (one wave per row).
__global__ __launch_bounds__(256) void prep_kernel(
    const float* __restrict__ X, unsigned short* __restrict__ Xb,
    float* __restrict__ sq, int* __restrict__ ap, int* __restrict__ an)
{
    const int t = blockIdx.x * 256 + threadIdx.x;
    if (t < NROWS) { ap[t] = 0; an[t] = 0x7f800000; }  // 0.0f / +inf
    const int row  = t >> 6;
    const int lane = t & 63;
    const f32x2 v = *(const f32x2*)(X + (size_t)row * DIMK + lane * 2);
    const unsigned short b0 = f2bf(v[0]);
    const unsigned short b1 = f2bf(v[1]);
    *(unsigned*)(Xb + (size_t)row * DIMK + lane * 2) =
        (unsigned)b0 | ((unsigned)b1 << 16);
    const float f0 = __uint_as_float((unsigned)b0 << 16);
    const float f1 = __uint_as_float((unsigned)b1 << 16);
    float s = f0 * f0 + f1 * f1;
    #pragma unroll
    for (int off = 32; off; off >>= 1) s += __shfl_xor(s, off);
    if (lane == 0) sq[row] = s;
}

// shifted row store: dist base is out+1, so per lane write [4rc-1, 4rc+3)
// (16B aligned) with the missing element pulled from the left neighbor.
// Each aligned 64B sector is fully covered within one instruction.
__device__ __forceinline__ void store_row_shifted(float* drow, f32x4 d4, int rc) {
    const float prev = __shfl_up(d4[3], 1);
    if (rc == 0) {
        drow[0] = d4[0];
        *(f32x2*)(drow + 1) = (f32x2){d4[1], d4[2]};
    } else {
        *(f32x4*)(drow + (rc << 2) - 1) = (f32x4){prev, d4[0], d4[1], d4[2]};
    }
    if (rc == 31)
        drow[127] = d4[3];
}

__global__ __launch_bounds__(256, 4) void dist_kernel(
    const unsigned short* __restrict__ Xb, const float* __restrict__ sq,
    const int* __restrict__ tgt, float* __restrict__ dist,
    int* __restrict__ ap, int* __restrict__ an)
{
    __shared__ __align__(16) char lds[32 * 1024];  // C half-tile f32 64x128

    const int t = threadIdx.x;
    const int bm = blockIdx.x, bn = blockIdx.y;    // bm FAST (v4 grid)
    const int lane = t & 63, wave = t >> 6;
    const int wm = (wave >> 1) << 6;               // wave's 64-row half
    const int wn = (wave & 1) << 6;                // wave's 64-col half
    const int l15 = lane & 15, quad = lane >> 4;
    const int rbase = bm << 7, cbase = bn << 7;
    const float INF = __int_as_float(0x7f800000);

    // ---- MFMA, operand-swapped (v6-verified): lane's f32x4 = 4 consecutive
    // cols (quad*4+reg) of row l15. Frags direct from global. ----
    f32x4 acc[4][4];
    #pragma unroll
    for (int mi = 0; mi < 4; mi++)
        #pragma unroll
        for (int ni = 0; ni < 4; ni++)
            acc[mi][ni] = (f32x4){0.f, 0.f, 0.f, 0.f};

    const unsigned short* Arow = Xb + (size_t)(rbase + wm + l15) * DIMK;
    const unsigned short* Brow = Xb + (size_t)(cbase + wn + l15) * DIMK;
    #pragma unroll
    for (int ks = 0; ks < 4; ks++) {
        const int kb = ks * 32 + quad * 8;
        bf16x8 af[4], bfr[4];
        #pragma unroll
        for (int mi = 0; mi < 4; mi++)
            af[mi] = *(const bf16x8*)(Arow + mi * 16 * DIMK + kb);
        #pragma unroll
        for (int ni = 0; ni < 4; ni++)
            bfr[ni] = *(const bf16x8*)(Brow + ni * 16 * DIMK + kb);
        #pragma unroll
        for (int mi = 0; mi < 4; mi++)
            #pragma unroll
            for (int ni = 0; ni < 4; ni++)
                acc[mi][ni] = __builtin_amdgcn_mfma_f32_16x16x32_bf16(
                    bfr[ni], af[mi], acc[mi][ni], 0, 0, 0);
    }

    // ---- convert sqd -> d in place + lane-local row reduce ----
    int rg[4]; float sqr[4]; int trg[4];
    #pragma unroll
    for (int mi = 0; mi < 4; mi++) {
        rg[mi]  = rbase + wm + mi * 16 + l15;
        sqr[mi] = sq[rg[mi]];
        trg[mi] = tgt[rg[mi]];
    }
    float apv[4] = {-1.f, -1.f, -1.f, -1.f};
    float anv[4] = {INF, INF, INF, INF};

    #pragma unroll
    for (int ni = 0; ni < 4; ni++) {
        const int c0 = cbase + wn + ni * 16 + quad * 4;   // global col base
        const f32x4 sqc = *(const f32x4*)(sq + c0);
        const i32x4 tc  = *(const i32x4*)(tgt + c0);
        #pragma unroll
        for (int mi = 0; mi < 4; mi++) {
            #pragma unroll
            for (int j = 0; j < 4; j++) {
                const float sqd = sqr[mi] + sqc[j] - 2.0f * acc[mi][ni][j];
                float d = sqd > 0.0f ? sqrtf(sqd) : 0.0f;
                if (rg[mi] == c0 + j) d = 0.0f;           // exact diagonal
                acc[mi][ni][j] = d;
                const bool same = (trg[mi] == tc[j]);
                apv[mi] = fmaxf(apv[mi], same ? d : -1.f);
                anv[mi] = fminf(anv[mi], same ? INF : d);
            }
        }
    }

    // combine the 4 quads holding the same row, one commit per row
    #pragma unroll
    for (int mi = 0; mi < 4; mi++) {
        apv[mi] = fmaxf(apv[mi], __shfl_xor(apv[mi], 16));
        apv[mi] = fmaxf(apv[mi], __shfl_xor(apv[mi], 32));
        anv[mi] = fminf(anv[mi], __shfl_xor(anv[mi], 16));
        anv[mi] = fminf(anv[mi], __shfl_xor(anv[mi], 32));
    }
    if (quad == 0) {
        #pragma unroll
        for (int mi = 0; mi < 4; mi++) {
            atomicMax(ap + rg[mi], __float_as_int(apv[mi]));
            atomicMin(an + rg[mi], __float_as_int(anv[mi]));
        }
    }

    // ---- C tile -> global in two 64-row halves through 32KB LDS ----
    const int rc = t & 31;                 // fixed 16B col-chunk
    const int w  = t >> 5;                 // row subset selector 0..7
    #pragma unroll
    for (int h = 0; h < 2; h++) {
        if (wm == h * 64) {                // the 2 waves owning rows of half h
            #pragma unroll
            for (int mi = 0; mi < 4; mi++) {
                const int rl = mi * 16 + l15;              // local row 0..63
                const int sw = (rl & 7) << 4;
                #pragma unroll
                for (int ni = 0; ni < 4; ni++) {
                    const int cb = (wn + ni * 16 + quad * 4) << 2;  // col byte
                    *(f32x4*)(lds + rl * 512 + (cb ^ sw)) = acc[mi][ni];
                }
            }
        }
        __syncthreads();
        #pragma unroll
        for (int it = 0; it < 8; it++) {
            const int r = it * 8 + w;      // local row 0..63
            const f32x4 d4 = *(const f32x4*)(
                lds + r * 512 + ((rc << 4) ^ ((r & 7) << 4)));
            const int rowg = rbase + h * 64 + r;
            store_row_shifted(dist + (size_t)rowg * NROWS + cbase, d4, rc);
        }
        __syncthreads();
    }
}

__global__ __launch_bounds__(256) void loss_kernel(
    const int* __restrict__ ap, const int* __restrict__ an,
    float* __restrict__ out)
{
    __shared__ float red[4];
    float s = 0.0f;
    for (int i = threadIdx.x; i < NROWS; i += 256) {
        const float v = __int_as_float(ap[i]) - __int_as_float(an[i]) + MARGIN;
        s += v > 0.0f ? v : 0.0f;
    }
    #pragma unroll
    for (int off = 32; off; off >>= 1) s += __shfl_xor(s, off);
    if ((threadIdx.x & 63) == 0) red[threadIdx.x >> 6] = s;
    __syncthreads();
    if (threadIdx.x == 0)
        out[0] = (red[0] + red[1] + red[2] + red[3]) * (1.0f / NROWS);
}

extern "C" void kernel_launch(void* const* d_in, const int* in_sizes, int n_in,
                              void* d_out, int out_size, void* d_ws, size_t ws_size,
                              hipStream_t stream)
{
    const float* X   = (const float*)d_in[0];
    const int*   tgt = (const int*)d_in[1];
    float*       out = (float*)d_out;

    // ws layout: Xb bf16 8192x128 linear (2 MB) | sq (32 KB) | ap | an
    unsigned short* Xb = (unsigned short*)d_ws;
    float* sq = (float*)((char*)d_ws + (size_t)NROWS * DIMK * 2);
    int*   ap = (int*)(sq + NROWS);
    int*   an = ap + NROWS;

    prep_kernel<<<(NROWS * 64) / 256, 256, 0, stream>>>(X, Xb, sq, ap, an);

    dim3 grid(64, 64);   // x = bm (fast): bn-seam neighbors share an XCD
    dist_kernel<<<grid, 256, 0, stream>>>(Xb, sq, tgt, out + 1, ap, an);

    loss_kernel<<<1, 256, 0, stream>>>(ap, an, out);
}